// Round 13
// baseline (177.862 us; speedup 1.0000x reference)
//
#include <hip/hip_runtime.h>

// GaussianMRIModel: splat 25000 anisotropic 3D Gaussians into 160^3 x 2 fp32.
// R18: revert R17 (dbuf staging: park stride 64B -> 1.15M bank conflicts,
// +20 live VGPR, 2x loop overhead; net regression). Base = R15 byte-for-byte
// (session best: 158.0us total / gather 84.8 / occ 62% / busy 86%).
// NEW (single change): heavy-first STATIC tile ordering (LPT). R15's tail:
// heavy tiles (up to CAP=384; ~190 pairs/wave after halving vs mean ~40) are
// raster-scattered through the 4000-block dispatch stream; one dispatched
// late extends the drain. make_queue (2-bucket: cnt>128 front, rest from the
// back, ~2us) builds a static permutation; gather reads tile = queue[...] --
// one extra scalar load, NO atomics in gather (R9's failure was the per-tile
// atomic pop chain + 1 tile/wave degeneracy, not the LPT idea).

namespace {
constexpr int GD = 160, GH = 160, GW = 160;
constexpr int NPTS = 25000;
constexpr int PATCH = 20;
constexpr int TS  = 8;               // tile edge
constexpr int TPD = GD / TS;         // 20
constexpr int NT  = TPD * TPD * TPD; // 8000 tiles
constexpr int CAP = 384;             // per-tile bucket capacity (mean ~81)
constexpr int PSTRIDE = 20;          // floats per gaussian struct (5x float4)
constexpr int HEAVY_THR = 128;       // cnt > THR -> front of queue
constexpr float L2E = 1.4426950408889634f;
}

typedef float f32x2 __attribute__((ext_vector_type(2)));

// tied in-place packed ops: no result-pair copyback
__device__ __forceinline__ void pk_fma_acc(f32x2& acc, f32x2 a, f32x2 b) {
    asm("v_pk_fma_f32 %0, %1, %2, %0" : "+v"(acc) : "v"(a), "v"(b));
}
__device__ __forceinline__ void pk_mul_ip(f32x2& d, f32x2 b) {
    asm("v_pk_mul_f32 %0, %0, %1" : "+v"(d) : "v"(b));
}

// Param struct (20 floats, 5x float4), coefficients pre-scaled by log2(e),
// -0.5 folded; gather computes t in exp2 space directly:
//  P0 = (q00, q01f, q02f, q11)
//  P1 = (q12f, q22, cvz, cvy)
//  P2 = (cvx, loPack, upPack, v)   loPack = loz|loy<<8|lox<<16|upz<<24
//  P3 = (r0, r0, r1, r1)           aligned broadcast pairs
//  P4 = (v2, 0, v4, v4)            (v4,v4) aligned pair; v = 2^(2*q00)

__global__ __launch_bounds__(256) void prep_bin(
    const float* __restrict__ centers,
    const float* __restrict__ log_scales,
    const float* __restrict__ quats,
    const float* __restrict__ rho,
    float* __restrict__ params,
    int* __restrict__ counts,
    unsigned short* __restrict__ list)
{
    const int t = blockIdx.x * 256 + threadIdx.x;   // grid = NPTS*64 threads
    const int gid  = t >> 6;
    const int lane = t & 63;

    // ---- all 64 lanes compute the gaussian's params redundantly ----
    const float r0 = rho[gid * 2 + 0];
    const float r1 = rho[gid * 2 + 1];
    const float s0 = __expf(log_scales[gid * 3 + 0]);
    const float s1 = __expf(log_scales[gid * 3 + 1]);
    const float s2 = __expf(log_scales[gid * 3 + 2]);

    const float smax = fmaxf(s0, fmaxf(s1, s2));
    const float rad  = smax * 3.0f;          // RADIUS_FACTOR
    const float amp2 = r0 * r0 + r1 * r1;

    const float cvz = centers[gid * 3 + 0] * (float)(GD - 1);
    const float cvy = centers[gid * 3 + 1] * (float)(GH - 1);
    const float cvx = centers[gid * 3 + 2] * (float)(GW - 1);

    const int bz = (int)floorf(cvz - rad);
    const int by = (int)floorf(cvy - rad);
    const int bx = (int)floorf(cvx - rad);
    const int hz = (int)ceilf(cvz + rad);
    const int hy = (int)ceilf(cvy + rad);
    const int hx = (int)ceilf(cvx + rad);

    // reference mask: idx>=0 && idx<dim && idx<=hi, idx in [base, base+19]
    const int loz = max(bz, 0), upz = min(min(hz, GD - 1), bz + PATCH - 1);
    const int loy = max(by, 0), upy = min(min(hy, GH - 1), by + PATCH - 1);
    const int lox = max(bx, 0), upx = min(min(hx, GW - 1), bx + PATCH - 1);

    const bool valid = (amp2 >= 1e-12f) && (rad >= 1e-3f) &&
                       (upz >= loz) && (upy >= loy) && (upx >= lox);

    const float q0 = quats[gid * 4 + 0], q1 = quats[gid * 4 + 1];
    const float q2 = quats[gid * 4 + 2], q3 = quats[gid * 4 + 3];
    float qn = sqrtf(q0 * q0 + q1 * q1 + q2 * q2 + q3 * q3);
    qn = fmaxf(qn, 1e-6f);
    const float w = q0 / qn, x = q1 / qn, y = q2 / qn, z = q3 / qn;

    const float R00 = w * w + x * x - y * y - z * z;
    const float R01 = 2.f * (x * y - w * z);
    const float R02 = 2.f * (x * z + w * y);
    const float R10 = 2.f * (x * y + w * z);
    const float R11 = w * w - x * x + y * y - z * z;
    const float R12 = 2.f * (y * z - w * x);
    const float R20 = 2.f * (x * z - w * y);
    const float R21 = 2.f * (y * z + w * x);
    const float R22 = w * w - x * x - y * y + z * z;

    const float c0 = fmaxf(s0, 1e-4f); const float i0 = 1.f / (c0 * c0);
    const float c1 = fmaxf(s1, 1e-4f); const float i1 = 1.f / (c1 * c1);
    const float c2 = fmaxf(s2, 1e-4f); const float i2 = 1.f / (c2 * c2);

    const float p00 = R00 * R00 * i0 + R01 * R01 * i1 + R02 * R02 * i2;
    const float p01 = R00 * R10 * i0 + R01 * R11 * i1 + R02 * R12 * i2;
    const float p02 = R00 * R20 * i0 + R01 * R21 * i1 + R02 * R22 * i2;
    const float p11 = R10 * R10 * i0 + R11 * R11 * i1 + R12 * R12 * i2;
    const float p12 = R10 * R20 * i0 + R11 * R21 * i1 + R12 * R22 * i2;
    const float p22 = R20 * R20 * i0 + R21 * R21 * i1 + R22 * R22 * i2;

    const float q00s = -0.5f * L2E * p00;
    const float v    = __builtin_amdgcn_exp2f(2.f * q00s);  // e^-p00
    const float v2   = v * v;
    const float v4   = v2 * v2;

    // invalid -> empty box (lo=255 > up=0): gather's masks reject all voxels
    const int zl = valid ? loz : 255, zu = valid ? upz : 0;
    const int yl = valid ? loy : 255, yu = valid ? upy : 0;
    const int xl = valid ? lox : 255, xu = valid ? upx : 0;
    const int loPack = zl | (yl << 8) | (xl << 16) | (zu << 24);
    const int upPack = yu | (xu << 8);

    if (lane == 0) {
        float4* P = reinterpret_cast<float4*>(params + (size_t)gid * PSTRIDE);
        P[0] = make_float4(q00s, -L2E * p01, -L2E * p02, -0.5f * L2E * p11);
        P[1] = make_float4(-L2E * p12, -0.5f * L2E * p22, cvz, cvy);
        P[2] = make_float4(cvx, __int_as_float(loPack), __int_as_float(upPack), v);
        P[3] = make_float4(r0, r0, r1, r1);
        P[4] = make_float4(v2, 0.f, v4, v4);
    }

    if (!valid) return;

    // ---- bin: one lane per candidate tile (box spans <=4 tiles per dim) ----
    const int tz0 = loz >> 3, tz1 = upz >> 3;
    const int ty0 = loy >> 3, ty1 = upy >> 3;
    const int tx0 = lox >> 3, tx1 = upx >> 3;
    const int tz = tz0 + (lane >> 4);
    const int ty = ty0 + ((lane >> 2) & 3);
    const int tx = tx0 + (lane & 3);
    if (tz > tz1 || ty > ty1 || tx > tx1) return;
    const int tile = (tz * TPD + ty) * TPD + tx;
    const int pos = atomicAdd(&counts[tile], 1);
    if (pos < CAP) list[(size_t)tile * CAP + pos] = (unsigned short)gid;
}

// 2-bucket LPT ordering: heavy tiles (cnt > HEAVY_THR) from the front,
// light tiles fill from the back. qc[0]=heavy ctr, qc[1]=light ctr
// (zeroed by the launch memset). Gather reads queue STATICALLY (no pop).
__global__ __launch_bounds__(256) void make_queue(
    const int* __restrict__ counts,
    int* __restrict__ queue,
    int* __restrict__ qc)
{
    const int t = blockIdx.x * 256 + threadIdx.x;
    if (t >= NT) return;
    if (counts[t] > HEAVY_THR) {
        queue[atomicAdd(&qc[0], 1)] = t;
    } else {
        queue[NT - 1 - atomicAdd(&qc[1], 1)] = t;
    }
}

__global__ __launch_bounds__(256, 6) void gather(
    const float* __restrict__ params,
    const int* __restrict__ counts,
    const unsigned short* __restrict__ list,
    const int* __restrict__ queue,
    float2* __restrict__ out)
{
    // 4 waves per block = 2 TILES, 2 waves per tile (half the gaussian list
    // each). grid = NT/2 = 4000 blocks; tile picked from the LPT queue so
    // heavy tiles start at t=0 (blocks dispatch roughly in order).
    const int wli  = threadIdx.x >> 6;
    const int lane = threadIdx.x & 63;
    const int h    = wli & 1;                        // which half of the list
    const int tile = __builtin_amdgcn_readfirstlane(
        queue[blockIdx.x * 2 + (wli >> 1)]);
    const int tz = tile / (TPD * TPD);
    const int rem = tile - tz * (TPD * TPD);
    const int ty = rem / TPD;
    const int tx = rem - ty * TPD;

    const int ly = lane >> 3, lx = lane & 7;
    const int iy = ty * TS + ly;
    const int ix = tx * TS + lx;
    const int z0 = tz * TS;
    const float fy = (float)iy, fx = (float)ix, fz = (float)z0;

    __shared__ float4 sP[4][64][5];   // per-wave 5 KB chunk; 20 KB/block

    int cnt = __builtin_amdgcn_readfirstlane(counts[tile]);
    if (cnt > CAP) cnt = CAP;
    const int half = (cnt + 1) >> 1;
    const int beg  = h ? half : 0;
    const int len  = h ? (cnt - half) : half;
    const float4* p4 = reinterpret_cast<const float4*>(params);
    const unsigned short* tl = list + (size_t)tile * CAP + beg;

    f32x2 Ar[4], Ai[4];               // Ar[k] = (ar[2k], ar[2k+1])
#pragma unroll
    for (int i = 0; i < 4; ++i) {
        Ar[i].x = 0.f; Ar[i].y = 0.f;
        Ai[i].x = 0.f; Ai[i].y = 0.f;
    }

    for (int b0 = 0; b0 < len; b0 += 64) {
        const int nb = min(64, len - b0);
        // per-wave staging: lane stages one full 80 B struct
        if (lane < nb) {
            const int g = tl[b0 + lane];
            const float4* src = p4 + (size_t)g * 5;
            sP[wli][lane][0] = src[0];
            sP[wli][lane][1] = src[1];
            sP[wli][lane][2] = src[2];
            sP[wli][lane][3] = src[3];
            sP[wli][lane][4] = src[4];
        }
        // same-wave ds_write -> ds_read: compiler-inserted lgkmcnt suffices
        for (int g = 0; g < nb; ++g) {
            const float4 Pa = sP[wli][g][0];
            const float4 Pb = sP[wli][g][1];
            const float4 Pc = sP[wli][g][2];
            const float4 Pd = sP[wli][g][3];
            const float4 Pe = sP[wli][g][4];
            // wave-uniform packed bounds -> SALU masking
            const int lo = __builtin_amdgcn_readfirstlane(__float_as_int(Pc.y));
            const int up = __builtin_amdgcn_readfirstlane(__float_as_int(Pc.z));
            const int loy_ = (lo >> 8) & 255, lox_ = (lo >> 16) & 255;
            const int upy_ = up & 255,        upx_ = (up >> 8) & 255;
            const int zl = (lo & 255) - z0;          // scalar, may be <0 or >7
            const int zu = ((lo >> 24) & 255) - z0;
            const bool yx = (iy >= loy_) & (iy <= upy_) &
                            (ix >= lox_) & (ix <= upx_);

            const float dy = fy - Pb.w;
            const float dx = fx - Pc.x;
            const float C = fmaf(dy, fmaf(Pa.w, dy, Pb.x * dx), Pb.y * dx * dx);
            const float B = fmaf(Pa.y, dy, Pa.z * dx);
            const float dz = fz - Pb.z;
            const float t0 = fmaf(dz, fmaf(Pa.x, dz, B), C);
            const float dt = fmaf(Pa.x, fmaf(2.f, dz, 1.f), B);
            const float w0 = __builtin_amdgcn_exp2f(t0);  // weight at z0
            const float u0 = __builtin_amdgcn_exp2f(dt);  // ratio at z0
            // fold y/x reject ONCE into w0 -> single cndmask
            const float w0m = yx ? w0 : 0.f;

            // stride-2 packed recurrence setup
            const float s0 = u0 * u0 * Pc.w;   // u0^2 * v
            const float s1 = s0 * Pe.x;        // * v^2
            f32x2 W;  W.x = w0m; W.y = w0m * u0;
            f32x2 S;  S.x = s0;  S.y = s1;
            f32x2 R0; R0.x = Pd.x; R0.y = Pd.y;   // (r0, r0) ready pair
            f32x2 R1; R1.x = Pd.z; R1.y = Pd.w;   // (r1, r1) ready pair
            f32x2 V4; V4.x = Pe.z; V4.y = Pe.w;   // (v4, v4) ready pair

            if (zl <= 0 && zu >= 7) {
                // box fully covers tile z-range: no per-step mask,
                // all ops in-place (zero copyback movs)
#pragma unroll
                for (int k = 0; k < 4; ++k) {
                    pk_fma_acc(Ar[k], W, R0);
                    pk_fma_acc(Ai[k], W, R1);
                    if (k < 3) { pk_mul_ip(W, S); pk_mul_ip(S, V4); }
                }
            } else {
#pragma unroll
                for (int k = 0; k < 4; ++k) {
                    f32x2 WM;
                    WM.x = (2 * k     >= zl && 2 * k     <= zu) ? W.x : 0.f;
                    WM.y = (2 * k + 1 >= zl && 2 * k + 1 <= zu) ? W.y : 0.f;
                    pk_fma_acc(Ar[k], WM, R0);
                    pk_fma_acc(Ai[k], WM, R1);
                    if (k < 3) { pk_mul_ip(W, S); pk_mul_ip(S, V4); }
                }
            }
        }
    }

    // ---- cross-wave combine: wave h=1 parks accums in its own (finished)
    // staging LDS (80B lane stride = bank-conflict-free, as R15); one
    // barrier; wave h=0 adds and stores. ----
    if (h == 1) {
        float4* dst = &sP[wli][lane][0];
        dst[0] = make_float4(Ar[0].x, Ar[0].y, Ai[0].x, Ai[0].y);
        dst[1] = make_float4(Ar[1].x, Ar[1].y, Ai[1].x, Ai[1].y);
        dst[2] = make_float4(Ar[2].x, Ar[2].y, Ai[2].x, Ai[2].y);
        dst[3] = make_float4(Ar[3].x, Ar[3].y, Ai[3].x, Ai[3].y);
    }
    __syncthreads();
    if (h == 0) {
        const float4* src = &sP[wli + 1][lane][0];
#pragma unroll
        for (int k = 0; k < 4; ++k) {
            const float4 p = src[k];
            Ar[k].x += p.x; Ar[k].y += p.y;
            Ai[k].x += p.z; Ai[k].y += p.w;
        }
#pragma unroll
        for (int k = 0; k < 4; ++k) {
            out[((size_t)(z0 + 2 * k)     * GH + iy) * GW + ix] =
                make_float2(Ar[k].x, Ai[k].x);
            out[((size_t)(z0 + 2 * k + 1) * GH + iy) * GW + ix] =
                make_float2(Ar[k].y, Ai[k].y);
        }
    }
}

extern "C" void kernel_launch(void* const* d_in, const int* in_sizes, int n_in,
                              void* d_out, int out_size, void* d_ws, size_t ws_size,
                              hipStream_t stream) {
    const float* centers    = (const float*)d_in[0];
    const float* log_scales = (const float*)d_in[1];
    const float* quats      = (const float*)d_in[2];
    const float* rho        = (const float*)d_in[3];

    // workspace: params (2.0 MB) | counts (32 KB) | qc (16 B) | queue (32 KB)
    //          | list (6.1 MB)
    float* params = (float*)d_ws;
    int* counts = (int*)(params + (size_t)NPTS * PSTRIDE);
    int* qc     = counts + NT;
    int* queue  = qc + 4;
    unsigned short* list = (unsigned short*)(queue + NT);

    // zero counts AND qc in one memset
    (void)hipMemsetAsync(counts, 0, (NT + 4) * sizeof(int), stream);
    prep_bin<<<(NPTS * 64) / 256, 256, 0, stream>>>(centers, log_scales, quats,
                                                    rho, params, counts, list);
    make_queue<<<(NT + 255) / 256, 256, 0, stream>>>(counts, queue, qc);
    // gather writes every voxel exactly once (wave h=0) -> no d_out memset
    gather<<<NT / 2, 256, 0, stream>>>(params, counts, list, queue,
                                       (float2*)d_out);
}

// Round 14
// 156.620 us; speedup vs baseline: 1.1356x; 1.1356x over previous
//
#include <hip/hip_runtime.h>

// GaussianMRIModel: splat 25000 anisotropic 3D Gaussians into 160^3 x 2 fp32.
// R19 = R15 byte-for-byte (session best: 158.0us total, gather 84.8us,
// occ 62%, VALUBusy 86%, 0 bank conflicts). Reverts R18's LPT queue (third
// scheduling-perturbation regression: adjacent queue entries paired heavy
// tiles into the same barrier-coupled block; +24% busy cycles).
// Structure: prep_bin (64-lane param compute + 1-lane-per-candidate-tile
// binning) | gather: 2 waves per tile with half the gaussian list each,
// 4000 blocks (> ~2048 resident -> scheduler refill), per-wave batch-64 LDS
// staging, tied in-place pk ops, dual-path packed stride-2 z-recurrence,
// LDS-park combine (80B stride, bank-conflict-free) + one barrier.
// Verdict ledger: work-split 2-way = WIN (+10%); branchless/z16/queue-pop/
// no-LDS/SALU-mask/4-way/dbuf/LPT = all regressions. R15 is the optimum.

namespace {
constexpr int GD = 160, GH = 160, GW = 160;
constexpr int NPTS = 25000;
constexpr int PATCH = 20;
constexpr int TS  = 8;               // tile edge
constexpr int TPD = GD / TS;         // 20
constexpr int NT  = TPD * TPD * TPD; // 8000 tiles
constexpr int CAP = 384;             // per-tile bucket capacity (mean ~81)
constexpr int PSTRIDE = 20;          // floats per gaussian struct (5x float4)
constexpr float L2E = 1.4426950408889634f;
}

typedef float f32x2 __attribute__((ext_vector_type(2)));

// tied in-place packed ops: no result-pair copyback
__device__ __forceinline__ void pk_fma_acc(f32x2& acc, f32x2 a, f32x2 b) {
    asm("v_pk_fma_f32 %0, %1, %2, %0" : "+v"(acc) : "v"(a), "v"(b));
}
__device__ __forceinline__ void pk_mul_ip(f32x2& d, f32x2 b) {
    asm("v_pk_mul_f32 %0, %0, %1" : "+v"(d) : "v"(b));
}

// Param struct (20 floats, 5x float4), coefficients pre-scaled by log2(e),
// -0.5 folded; gather computes t in exp2 space directly:
//  P0 = (q00, q01f, q02f, q11)
//  P1 = (q12f, q22, cvz, cvy)
//  P2 = (cvx, loPack, upPack, v)   loPack = loz|loy<<8|lox<<16|upz<<24
//  P3 = (r0, r0, r1, r1)           aligned broadcast pairs
//  P4 = (v2, 0, v4, v4)            (v4,v4) aligned pair; v = 2^(2*q00)

__global__ __launch_bounds__(256) void prep_bin(
    const float* __restrict__ centers,
    const float* __restrict__ log_scales,
    const float* __restrict__ quats,
    const float* __restrict__ rho,
    float* __restrict__ params,
    int* __restrict__ counts,
    unsigned short* __restrict__ list)
{
    const int t = blockIdx.x * 256 + threadIdx.x;   // grid = NPTS*64 threads
    const int gid  = t >> 6;
    const int lane = t & 63;

    // ---- all 64 lanes compute the gaussian's params redundantly ----
    const float r0 = rho[gid * 2 + 0];
    const float r1 = rho[gid * 2 + 1];
    const float s0 = __expf(log_scales[gid * 3 + 0]);
    const float s1 = __expf(log_scales[gid * 3 + 1]);
    const float s2 = __expf(log_scales[gid * 3 + 2]);

    const float smax = fmaxf(s0, fmaxf(s1, s2));
    const float rad  = smax * 3.0f;          // RADIUS_FACTOR
    const float amp2 = r0 * r0 + r1 * r1;

    const float cvz = centers[gid * 3 + 0] * (float)(GD - 1);
    const float cvy = centers[gid * 3 + 1] * (float)(GH - 1);
    const float cvx = centers[gid * 3 + 2] * (float)(GW - 1);

    const int bz = (int)floorf(cvz - rad);
    const int by = (int)floorf(cvy - rad);
    const int bx = (int)floorf(cvx - rad);
    const int hz = (int)ceilf(cvz + rad);
    const int hy = (int)ceilf(cvy + rad);
    const int hx = (int)ceilf(cvx + rad);

    // reference mask: idx>=0 && idx<dim && idx<=hi, idx in [base, base+19]
    const int loz = max(bz, 0), upz = min(min(hz, GD - 1), bz + PATCH - 1);
    const int loy = max(by, 0), upy = min(min(hy, GH - 1), by + PATCH - 1);
    const int lox = max(bx, 0), upx = min(min(hx, GW - 1), bx + PATCH - 1);

    const bool valid = (amp2 >= 1e-12f) && (rad >= 1e-3f) &&
                       (upz >= loz) && (upy >= loy) && (upx >= lox);

    const float q0 = quats[gid * 4 + 0], q1 = quats[gid * 4 + 1];
    const float q2 = quats[gid * 4 + 2], q3 = quats[gid * 4 + 3];
    float qn = sqrtf(q0 * q0 + q1 * q1 + q2 * q2 + q3 * q3);
    qn = fmaxf(qn, 1e-6f);
    const float w = q0 / qn, x = q1 / qn, y = q2 / qn, z = q3 / qn;

    const float R00 = w * w + x * x - y * y - z * z;
    const float R01 = 2.f * (x * y - w * z);
    const float R02 = 2.f * (x * z + w * y);
    const float R10 = 2.f * (x * y + w * z);
    const float R11 = w * w - x * x + y * y - z * z;
    const float R12 = 2.f * (y * z - w * x);
    const float R20 = 2.f * (x * z - w * y);
    const float R21 = 2.f * (y * z + w * x);
    const float R22 = w * w - x * x - y * y + z * z;

    const float c0 = fmaxf(s0, 1e-4f); const float i0 = 1.f / (c0 * c0);
    const float c1 = fmaxf(s1, 1e-4f); const float i1 = 1.f / (c1 * c1);
    const float c2 = fmaxf(s2, 1e-4f); const float i2 = 1.f / (c2 * c2);

    const float p00 = R00 * R00 * i0 + R01 * R01 * i1 + R02 * R02 * i2;
    const float p01 = R00 * R10 * i0 + R01 * R11 * i1 + R02 * R12 * i2;
    const float p02 = R00 * R20 * i0 + R01 * R21 * i1 + R02 * R22 * i2;
    const float p11 = R10 * R10 * i0 + R11 * R11 * i1 + R12 * R12 * i2;
    const float p12 = R10 * R20 * i0 + R11 * R21 * i1 + R12 * R22 * i2;
    const float p22 = R20 * R20 * i0 + R21 * R21 * i1 + R22 * R22 * i2;

    const float q00s = -0.5f * L2E * p00;
    const float v    = __builtin_amdgcn_exp2f(2.f * q00s);  // e^-p00
    const float v2   = v * v;
    const float v4   = v2 * v2;

    // invalid -> empty box (lo=255 > up=0): gather's masks reject all voxels
    const int zl = valid ? loz : 255, zu = valid ? upz : 0;
    const int yl = valid ? loy : 255, yu = valid ? upy : 0;
    const int xl = valid ? lox : 255, xu = valid ? upx : 0;
    const int loPack = zl | (yl << 8) | (xl << 16) | (zu << 24);
    const int upPack = yu | (xu << 8);

    if (lane == 0) {
        float4* P = reinterpret_cast<float4*>(params + (size_t)gid * PSTRIDE);
        P[0] = make_float4(q00s, -L2E * p01, -L2E * p02, -0.5f * L2E * p11);
        P[1] = make_float4(-L2E * p12, -0.5f * L2E * p22, cvz, cvy);
        P[2] = make_float4(cvx, __int_as_float(loPack), __int_as_float(upPack), v);
        P[3] = make_float4(r0, r0, r1, r1);
        P[4] = make_float4(v2, 0.f, v4, v4);
    }

    if (!valid) return;

    // ---- bin: one lane per candidate tile (box spans <=4 tiles per dim) ----
    const int tz0 = loz >> 3, tz1 = upz >> 3;
    const int ty0 = loy >> 3, ty1 = upy >> 3;
    const int tx0 = lox >> 3, tx1 = upx >> 3;
    const int tz = tz0 + (lane >> 4);
    const int ty = ty0 + ((lane >> 2) & 3);
    const int tx = tx0 + (lane & 3);
    if (tz > tz1 || ty > ty1 || tx > tx1) return;
    const int tile = (tz * TPD + ty) * TPD + tx;
    const int pos = atomicAdd(&counts[tile], 1);
    if (pos < CAP) list[(size_t)tile * CAP + pos] = (unsigned short)gid;
}

__global__ __launch_bounds__(256, 6) void gather(
    const float* __restrict__ params,
    const int* __restrict__ counts,
    const unsigned short* __restrict__ list,
    float2* __restrict__ out)
{
    // 4 waves per block = 2 TILES, 2 waves per tile (half the gaussian list
    // each). grid = NT/2 = 4000 blocks > ~2048 resident -> scheduler refill.
    const int wli  = threadIdx.x >> 6;
    const int lane = threadIdx.x & 63;
    const int h    = wli & 1;                        // which half of the list
    const int tile = blockIdx.x * 2 + (wli >> 1);
    const int tz = tile / (TPD * TPD);
    const int rem = tile - tz * (TPD * TPD);
    const int ty = rem / TPD;
    const int tx = rem - ty * TPD;

    const int ly = lane >> 3, lx = lane & 7;
    const int iy = ty * TS + ly;
    const int ix = tx * TS + lx;
    const int z0 = tz * TS;
    const float fy = (float)iy, fx = (float)ix, fz = (float)z0;

    __shared__ float4 sP[4][64][5];   // per-wave 5 KB chunk; 20 KB/block

    int cnt = __builtin_amdgcn_readfirstlane(counts[tile]);
    if (cnt > CAP) cnt = CAP;
    const int half = (cnt + 1) >> 1;
    const int beg  = h ? half : 0;
    const int len  = h ? (cnt - half) : half;
    const float4* p4 = reinterpret_cast<const float4*>(params);
    const unsigned short* tl = list + (size_t)tile * CAP + beg;

    f32x2 Ar[4], Ai[4];               // Ar[k] = (ar[2k], ar[2k+1])
#pragma unroll
    for (int i = 0; i < 4; ++i) {
        Ar[i].x = 0.f; Ar[i].y = 0.f;
        Ai[i].x = 0.f; Ai[i].y = 0.f;
    }

    for (int b0 = 0; b0 < len; b0 += 64) {
        const int nb = min(64, len - b0);
        // per-wave staging: lane stages one full 80 B struct
        if (lane < nb) {
            const int g = tl[b0 + lane];
            const float4* src = p4 + (size_t)g * 5;
            sP[wli][lane][0] = src[0];
            sP[wli][lane][1] = src[1];
            sP[wli][lane][2] = src[2];
            sP[wli][lane][3] = src[3];
            sP[wli][lane][4] = src[4];
        }
        // same-wave ds_write -> ds_read: compiler-inserted lgkmcnt suffices
        for (int g = 0; g < nb; ++g) {
            const float4 Pa = sP[wli][g][0];
            const float4 Pb = sP[wli][g][1];
            const float4 Pc = sP[wli][g][2];
            const float4 Pd = sP[wli][g][3];
            const float4 Pe = sP[wli][g][4];
            // wave-uniform packed bounds -> SALU masking
            const int lo = __builtin_amdgcn_readfirstlane(__float_as_int(Pc.y));
            const int up = __builtin_amdgcn_readfirstlane(__float_as_int(Pc.z));
            const int loy_ = (lo >> 8) & 255, lox_ = (lo >> 16) & 255;
            const int upy_ = up & 255,        upx_ = (up >> 8) & 255;
            const int zl = (lo & 255) - z0;          // scalar, may be <0 or >7
            const int zu = ((lo >> 24) & 255) - z0;
            const bool yx = (iy >= loy_) & (iy <= upy_) &
                            (ix >= lox_) & (ix <= upx_);

            const float dy = fy - Pb.w;
            const float dx = fx - Pc.x;
            const float C = fmaf(dy, fmaf(Pa.w, dy, Pb.x * dx), Pb.y * dx * dx);
            const float B = fmaf(Pa.y, dy, Pa.z * dx);
            const float dz = fz - Pb.z;
            const float t0 = fmaf(dz, fmaf(Pa.x, dz, B), C);
            const float dt = fmaf(Pa.x, fmaf(2.f, dz, 1.f), B);
            const float w0 = __builtin_amdgcn_exp2f(t0);  // weight at z0
            const float u0 = __builtin_amdgcn_exp2f(dt);  // ratio at z0
            // fold y/x reject ONCE into w0 -> single cndmask
            const float w0m = yx ? w0 : 0.f;

            // stride-2 packed recurrence setup
            const float s0 = u0 * u0 * Pc.w;   // u0^2 * v
            const float s1 = s0 * Pe.x;        // * v^2
            f32x2 W;  W.x = w0m; W.y = w0m * u0;
            f32x2 S;  S.x = s0;  S.y = s1;
            f32x2 R0; R0.x = Pd.x; R0.y = Pd.y;   // (r0, r0) ready pair
            f32x2 R1; R1.x = Pd.z; R1.y = Pd.w;   // (r1, r1) ready pair
            f32x2 V4; V4.x = Pe.z; V4.y = Pe.w;   // (v4, v4) ready pair

            if (zl <= 0 && zu >= 7) {
                // box fully covers tile z-range: no per-step mask,
                // all ops in-place (zero copyback movs)
#pragma unroll
                for (int k = 0; k < 4; ++k) {
                    pk_fma_acc(Ar[k], W, R0);
                    pk_fma_acc(Ai[k], W, R1);
                    if (k < 3) { pk_mul_ip(W, S); pk_mul_ip(S, V4); }
                }
            } else {
#pragma unroll
                for (int k = 0; k < 4; ++k) {
                    f32x2 WM;
                    WM.x = (2 * k     >= zl && 2 * k     <= zu) ? W.x : 0.f;
                    WM.y = (2 * k + 1 >= zl && 2 * k + 1 <= zu) ? W.y : 0.f;
                    pk_fma_acc(Ar[k], WM, R0);
                    pk_fma_acc(Ai[k], WM, R1);
                    if (k < 3) { pk_mul_ip(W, S); pk_mul_ip(S, V4); }
                }
            }
        }
    }

    // ---- cross-wave combine: wave h=1 parks accums in its own (finished)
    // staging LDS (80B lane stride = bank-conflict-free); one barrier;
    // wave h=0 adds and stores. ----
    if (h == 1) {
        float4* dst = &sP[wli][lane][0];
        dst[0] = make_float4(Ar[0].x, Ar[0].y, Ai[0].x, Ai[0].y);
        dst[1] = make_float4(Ar[1].x, Ar[1].y, Ai[1].x, Ai[1].y);
        dst[2] = make_float4(Ar[2].x, Ar[2].y, Ai[2].x, Ai[2].y);
        dst[3] = make_float4(Ar[3].x, Ar[3].y, Ai[3].x, Ai[3].y);
    }
    __syncthreads();
    if (h == 0) {
        const float4* src = &sP[wli + 1][lane][0];
#pragma unroll
        for (int k = 0; k < 4; ++k) {
            const float4 p = src[k];
            Ar[k].x += p.x; Ar[k].y += p.y;
            Ai[k].x += p.z; Ai[k].y += p.w;
        }
#pragma unroll
        for (int k = 0; k < 4; ++k) {
            out[((size_t)(z0 + 2 * k)     * GH + iy) * GW + ix] =
                make_float2(Ar[k].x, Ai[k].x);
            out[((size_t)(z0 + 2 * k + 1) * GH + iy) * GW + ix] =
                make_float2(Ar[k].y, Ai[k].y);
        }
    }
}

extern "C" void kernel_launch(void* const* d_in, const int* in_sizes, int n_in,
                              void* d_out, int out_size, void* d_ws, size_t ws_size,
                              hipStream_t stream) {
    const float* centers    = (const float*)d_in[0];
    const float* log_scales = (const float*)d_in[1];
    const float* quats      = (const float*)d_in[2];
    const float* rho        = (const float*)d_in[3];

    // workspace: params (2.0 MB) | counts (32 KB) | list (6.1 MB)
    float* params = (float*)d_ws;
    int* counts = (int*)(params + (size_t)NPTS * PSTRIDE);
    unsigned short* list = (unsigned short*)(counts + NT);

    (void)hipMemsetAsync(counts, 0, NT * sizeof(int), stream);
    prep_bin<<<(NPTS * 64) / 256, 256, 0, stream>>>(centers, log_scales, quats,
                                                    rho, params, counts, list);
    // gather writes every voxel exactly once (wave h=0) -> no d_out memset
    gather<<<NT / 2, 256, 0, stream>>>(params, counts, list, (float2*)d_out);
}